// Round 4
// baseline (31.099 us; speedup 1.0000x reference)
//
#include <hip/hip_runtime.h>

#define NPATCH  64
#define NB1     10
#define NBT     16
#define MOUT    9        // NB1-1
#define OUTD    5760     // NPATCH*NB1*MOUT
#define EPS2f   0.001f
#define LN2f    0.69314718055994530942f

// d_ws layout (float offsets)
#define W1_OFF  0                       // [640][9][16][16]  = 1,474,560 floats
#define WF_OFF  1474560                 // [640][9][16]      =    92,160 floats
#define XT_OFF  1566720                 // [64 p][10 c][64 b][16 s] = 655,360
// total 2,222,080 floats = 8.89 MB  (ws is 268 MB)

// ---------------------------------------------------------------------------
// Prep: W1/Wf sigmoid tables + x transpose. 704 blocks x 256.
__global__ __launch_bounds__(256) void prep_kernel(
    const float* __restrict__ x,
    const float* __restrict__ bound1,
    const float* __restrict__ bound2,
    float* __restrict__ ws)
{
    const int bid = blockIdx.x;
    const int tid = threadIdx.x;

    if (bid < 640) {                       // sigmoid tables for pj = bid
        const int pj = bid;
        const int bb = pj * MOUT;
        float* w1 = ws + W1_OFF + (size_t)pj * (MOUT * 256);
        float* wf = ws + WF_OFF + (size_t)pj * (MOUT * 16);
        for (int i = tid; i < MOUT * 256; i += 256) {   // 9 iters
            const int m = i >> 8;
            const int r = i & 255;
            const int t = r >> 4;
            const int s = r & 15;
            const float b1v = bound1[bb + m];
            const float b2v = bound2[bb + m];
            const float Ws  = fminf(b1v, b2v);          // W_start
            const float z   = ((float)s - Ws) * ((float)t - EPS2f - (float)s);
            w1[i] = __builtin_amdgcn_rcpf(1.0f + __expf(-z));
        }
        if (tid < MOUT * NBT) {
            const int m = tid >> 4;
            const int t = tid & 15;
            const float b1v = bound1[bb + m];
            const float b2v = bound2[bb + m];
            const float Ws  = fminf(b1v, b2v);
            const float We  = fmaxf(b1v, b2v);          // W_end
            const float z   = ((float)t - Ws) * (We - (float)t);
            wf[tid] = __builtin_amdgcn_rcpf(1.0f + __expf(-z));
        }
    } else {                               // transpose patch p = bid-640
        const int p = bid - 640;
        float* xt = ws + XT_OFF;
        for (int idx = tid; idx < 64 * 160; idx += 256) {   // 40 iters
            const int b = idx / 160;
            const int i = idx - b * 160;
            const int s = i / NB1;
            const int c = i - s * NB1;
            // xT[p][c][b][s] <- x[b][p*160 + s*10 + c]   (reads coalesced)
            xt[(((size_t)(p * NB1 + c) * 64) + b) * NBT + s] =
                x[(size_t)b * (NPATCH * 160) + p * 160 + i];
        }
    }
}

// ---------------------------------------------------------------------------
// Main: wave = one (pj, m); lane = batch. No LDS, no barriers.
// 1440 blocks x 256 (4 waves/block); VGPR capped at 128 -> 16 waves/CU.
__global__ __launch_bounds__(256, 4) void until_kernel(
    const float* __restrict__ ws,
    float* __restrict__ out)
{
    const int tid  = threadIdx.x;
    const int wid  = tid >> 6;
    const int lane = tid & 63;             // batch index

    int g = blockIdx.x * 4 + wid;          // 0..5759 = (pj, m) flat
    g = __builtin_amdgcn_readfirstlane(g); // scalarize all table addressing
    const int pj = g / 9;
    const int m  = g - pj * 9;
    const int p  = pj / NB1;
    const int j  = pj - p * NB1;
    const int k  = (m < j) ? m : m + 1;    // kidx[j][m]

    const float* xt = ws + XT_OFF;
    const float* w1 = ws + W1_OFF + (size_t)g * 256;   // (pj*9+m)*256
    const float* wf = ws + WF_OFF + (size_t)g * 16;

    // per-lane x fragments: 4 coalesced dwordx4 each (16B/lane rows)
    const float4* xj4 = reinterpret_cast<const float4*>(
        xt + (((size_t)(p * NB1 + j) * 64) + lane) * NBT);
    const float4* xk4 = reinterpret_cast<const float4*>(
        xt + (((size_t)(p * NB1 + k) * 64) + lane) * NBT);

    float xtj[NBT], na[NBT];               // na = x_other - 1
    #pragma unroll
    for (int q = 0; q < 4; ++q) {
        const float4 vj = xj4[q];
        xtj[4 * q + 0] = vj.x; xtj[4 * q + 1] = vj.y;
        xtj[4 * q + 2] = vj.z; xtj[4 * q + 3] = vj.w;
        const float4 vk = xk4[q];
        na[4 * q + 0] = vk.x - 1.0f; na[4 * q + 1] = vk.y - 1.0f;
        na[4 * q + 2] = vk.z - 1.0f; na[4 * q + 3] = vk.w - 1.0f;
    }

    float wfr[NBT];                        // wave-uniform loads
    {
        const float4* wf4 = reinterpret_cast<const float4*>(wf);
        #pragma unroll
        for (int q = 0; q < 4; ++q) {
            const float4 v = wf4[q];
            wfr[4 * q + 0] = v.x; wfr[4 * q + 1] = v.y;
            wfr[4 * q + 2] = v.z; wfr[4 * q + 3] = v.w;
        }
    }

    const float4* w1row = reinterpret_cast<const float4*>(w1);

    float qacc = 1.0f;
    #pragma unroll
    for (int t = 0; t < NBT; ++t) {
        // 4 wave-uniform 16B loads (scalar-promotable: const restrict, SGPR addr)
        const float4 wa = w1row[t * 4 + 0];
        const float4 wb = w1row[t * 4 + 1];
        const float4 wc = w1row[t * 4 + 2];
        const float4 wd = w1row[t * 4 + 3];
        float wv[NBT];
        wv[0]=wa.x; wv[1]=wa.y; wv[2]=wa.z; wv[3]=wa.w;
        wv[4]=wb.x; wv[5]=wb.y; wv[6]=wb.z; wv[7]=wb.w;
        wv[8]=wc.x; wv[9]=wc.y; wv[10]=wc.z; wv[11]=wc.w;
        wv[12]=wd.x; wv[13]=wd.y; wv[14]=wd.z; wv[15]=wd.w;

        float e[NBT];
        #pragma unroll
        for (int s = 0; s < NBT; ++s)
            e[s] = fmaf(na[s], wv[s], 1.0f);       // X1 = 1 - (1-x)*W1

        const float m0 = (e[0]  * e[1])  * (e[2]  * e[3]);
        const float m1 = (e[4]  * e[5])  * (e[6]  * e[7]);
        const float m2 = (e[8]  * e[9])  * (e[10] * e[11]);
        const float m3 = (e[12] * e[13]) * (e[14] * e[15]);
        const float pr = (m0 * m1) * (m2 * m3);    // prod_s X1

        // x_layer2 = 1/(1 - ln P); P=0 -> log2=-inf -> rcp(+inf)=0 (exact limit)
        const float lp2 = __log2f(pr);
        const float xl2 = __builtin_amdgcn_rcpf(fmaf(-LN2f, lp2, 1.0f));
        const float u   = xtj[t] * xl2 * wfr[t];
        qacc = fmaf(-qacc, u, qacc);               // qacc *= (1 - u)
    }

    // out = 1 + 1/(S-1), S = ln qacc; qacc=0 -> rcp(-inf)=-0 -> out=1 (limit)
    const float S     = LN2f * __log2f(qacc);
    const float out_v = 1.0f + __builtin_amdgcn_rcpf(S - 1.0f);

    out[(size_t)lane * OUTD + (size_t)pj * MOUT + m] = out_v;
}

extern "C" void kernel_launch(void* const* d_in, const int* in_sizes, int n_in,
                              void* d_out, int out_size, void* d_ws, size_t ws_size,
                              hipStream_t stream) {
    const float* x  = (const float*)d_in[0];
    const float* b1 = (const float*)d_in[1];
    const float* b2 = (const float*)d_in[2];
    float* ws  = (float*)d_ws;
    float* out = (float*)d_out;
    prep_kernel<<<dim3(704), dim3(256), 0, stream>>>(x, b1, b2, ws);
    until_kernel<<<dim3(1440), dim3(256), 0, stream>>>(ws, out);
}

// Round 5
// 17.173 us; speedup vs baseline: 1.8109x; 1.8109x over previous
//
#include <hip/hip_runtime.h>

#define NPATCH  64
#define NB1     10
#define NBT     16
#define MOUT    9        // NB1-1
#define ROWLEN  160      // NBT*NB1
#define ROWPAD  161      // 161 % 32 == 1 -> conflict-free column gathers
#define OUTD    5760     // NPATCH*NB1*MOUT
#define EPS2f   0.001f
#define LN2f    0.69314718055994530942f

// Block = pj (640 blocks), 576 threads = 9 waves; wave = m, lane = batch.
// Register-lean (~50 VGPR) + __launch_bounds__(576,7) -> VGPR<=64 ->
// 3 blocks/CU (27 waves/CU), all 640 blocks co-resident in ONE round.
// LDS/block = 41216 + 9216 + 576 + 2304 = 53312 B; 3x = 159.9 KB <= 160 KB.
__global__ __launch_bounds__(576, 7) void until_kernel(
    const float* __restrict__ x,
    const float* __restrict__ bound1,
    const float* __restrict__ bound2,
    float* __restrict__ out)
{
    __shared__ float xs[64][ROWPAD];                       // 41.2 KB
    __shared__ __align__(16) float w1s[MOUT][NBT][NBT];    // 9.2 KB
    __shared__ __align__(16) float wfs[MOUT][NBT];         // 576 B
    __shared__ float ob[576];                              // 2.3 KB

    const int tid = threadIdx.x;
    const int pj  = blockIdx.x;       // 0..639
    const int p   = pj / NB1;
    const int j   = pj - p * NB1;

    // ---- stage all 64 batch rows of patch p (coalesced float4)
    for (int i = tid; i < 64 * (ROWLEN / 4); i += 576) {
        const int b4 = i / 40;
        const int c4 = (i - b4 * 40) * 4;
        const float4 v = *reinterpret_cast<const float4*>(
            x + (size_t)b4 * (NPATCH * ROWLEN) + p * ROWLEN + c4);
        xs[b4][c4 + 0] = v.x;
        xs[b4][c4 + 1] = v.y;
        xs[b4][c4 + 2] = v.z;
        xs[b4][c4 + 3] = v.w;
    }

    // ---- batch-independent W1 / Wf tables for this (p,j)  (exactly 4 iters)
    const int bb = pj * MOUT;
    for (int i = tid; i < MOUT * NBT * NBT; i += 576) {
        const int mi = i >> 8;
        const int r  = i & 255;
        const int t  = r >> 4;
        const int s  = r & 15;
        const float b1v = bound1[bb + mi];
        const float b2v = bound2[bb + mi];
        const float Ws  = fminf(b1v, b2v);                  // W_start
        const float z   = ((float)s - Ws) * ((float)t - EPS2f - (float)s);
        w1s[mi][t][s] = __builtin_amdgcn_rcpf(1.0f + __expf(-z));
    }
    if (tid < MOUT * NBT) {
        const int mi = tid >> 4;
        const int t  = tid & 15;
        const float b1v = bound1[bb + mi];
        const float b2v = bound2[bb + mi];
        const float Ws  = fminf(b1v, b2v);
        const float We  = fmaxf(b1v, b2v);                  // W_end
        const float z   = ((float)t - Ws) * (We - (float)t);
        wfs[mi][t] = __builtin_amdgcn_rcpf(1.0f + __expf(-z));
    }

    __syncthreads();

    // ---- compute: wave = m, lane = batch
    const int m    = tid >> 6;        // 0..8
    const int lane = tid & 63;        // batch
    const int k    = (m < j) ? m : m + 1;   // kidx[j][m]

    // na = x_other - 1 : the only big register array (16 VGPR).
    // addr = lane*161 + const -> 2 lanes/bank aliasing = free.
    float na[NBT];
    #pragma unroll
    for (int s = 0; s < NBT; ++s)
        na[s] = xs[lane][s * NB1 + k] - 1.0f;

    const float4* w1row = reinterpret_cast<const float4*>(&w1s[m][0][0]);

    float qacc = 1.0f;
    #pragma unroll
    for (int t = 0; t < NBT; ++t) {
        // 4 wave-uniform ds_read_b128 (broadcast, minimal bank traffic)
        const float4 wa = w1row[t * 4 + 0];
        const float4 wb = w1row[t * 4 + 1];
        const float4 wc = w1row[t * 4 + 2];
        const float4 wd = w1row[t * 4 + 3];

        float e[NBT];
        e[0]  = fmaf(na[0],  wa.x, 1.0f);
        e[1]  = fmaf(na[1],  wa.y, 1.0f);
        e[2]  = fmaf(na[2],  wa.z, 1.0f);
        e[3]  = fmaf(na[3],  wa.w, 1.0f);
        e[4]  = fmaf(na[4],  wb.x, 1.0f);
        e[5]  = fmaf(na[5],  wb.y, 1.0f);
        e[6]  = fmaf(na[6],  wb.z, 1.0f);
        e[7]  = fmaf(na[7],  wb.w, 1.0f);
        e[8]  = fmaf(na[8],  wc.x, 1.0f);
        e[9]  = fmaf(na[9],  wc.y, 1.0f);
        e[10] = fmaf(na[10], wc.z, 1.0f);
        e[11] = fmaf(na[11], wc.w, 1.0f);
        e[12] = fmaf(na[12], wd.x, 1.0f);
        e[13] = fmaf(na[13], wd.y, 1.0f);
        e[14] = fmaf(na[14], wd.z, 1.0f);
        e[15] = fmaf(na[15], wd.w, 1.0f);

        const float m0 = (e[0]  * e[1])  * (e[2]  * e[3]);
        const float m1 = (e[4]  * e[5])  * (e[6]  * e[7]);
        const float m2 = (e[8]  * e[9])  * (e[10] * e[11]);
        const float m3 = (e[12] * e[13]) * (e[14] * e[15]);
        const float pr = (m0 * m1) * (m2 * m3);    // prod_s X1

        // x_layer2 = 1/(1 - ln P); P=0 -> log2=-inf -> rcp(+inf)=0 (exact limit)
        const float lp2 = __log2f(pr);
        const float xl2 = __builtin_amdgcn_rcpf(fmaf(-LN2f, lp2, 1.0f));

        // re-read per t instead of caching 32 floats in VGPRs:
        const float xt_t = xs[lane][t * NB1 + j];  // per-lane, conflict-free
        const float wf_t = wfs[m][t];              // wave-uniform broadcast
        const float u    = xt_t * xl2 * wf_t;
        qacc = fmaf(-qacc, u, qacc);               // qacc *= (1 - u)
    }

    // out = 1 + 1/(S-1), S = ln qacc; qacc=0 -> rcp(-inf)=-0 -> out=1 (limit)
    const float S     = LN2f * __log2f(qacc);
    const float out_v = 1.0f + __builtin_amdgcn_rcpf(S - 1.0f);

    ob[lane * MOUT + m] = out_v;      // stride 9, gcd(9,32)=1 -> 2-way = free
    __syncthreads();

    // consecutive lanes -> consecutive flat out indices (9-float row chunks)
    {
        const int bo = tid / MOUT;
        const int mo = tid - bo * MOUT;
        out[(size_t)bo * OUTD + bb + mo] = ob[tid];
    }
}

extern "C" void kernel_launch(void* const* d_in, const int* in_sizes, int n_in,
                              void* d_out, int out_size, void* d_ws, size_t ws_size,
                              hipStream_t stream) {
    const float* x  = (const float*)d_in[0];
    const float* b1 = (const float*)d_in[1];
    const float* b2 = (const float*)d_in[2];
    float* out = (float*)d_out;
    until_kernel<<<dim3(NPATCH * NB1), dim3(576), 0, stream>>>(x, b1, b2, out);
}

// Round 6
// 16.182 us; speedup vs baseline: 1.9218x; 1.0613x over previous
//
#include <hip/hip_runtime.h>

#define NPATCH  64
#define NB1     10
#define NBT     16
#define MOUT    9        // NB1-1
#define ROWLEN  160      // NBT*NB1
#define ROWPAD  161      // 161 % 32 == 1 -> conflict-free column gathers
#define OUTD    5760     // NPATCH*NB1*MOUT
#define EPS2f   0.001f
#define LN2f    0.69314718055994530942f

typedef float f32x2 __attribute__((ext_vector_type(2)));

static __device__ __forceinline__ f32x2 pk_fma(f32x2 a, f32x2 b, f32x2 c) {
    f32x2 d;
    asm("v_pk_fma_f32 %0, %1, %2, %3" : "=v"(d) : "v"(a), "v"(b), "v"(c));
    return d;
}
static __device__ __forceinline__ f32x2 pk_mul(f32x2 a, f32x2 b) {
    f32x2 d;
    asm("v_pk_mul_f32 %0, %1, %2" : "=v"(d) : "v"(a), "v"(b));
    return d;
}

// Block = pj (640 blocks), 576 threads = 9 waves; wave = m, lane = batch.
// Lean registers (~50 VGPR) + __launch_bounds__(576,7) -> 3 blocks/CU,
// all 640 blocks co-resident (27 waves/CU), zero dispatch tail.
// LDS/block = 41216 + 9216 + 576 + 2304 = 53312 B; 3x = 159.9 KB <= 160 KB.
__global__ __launch_bounds__(576, 7) void until_kernel(
    const float* __restrict__ x,
    const float* __restrict__ bound1,
    const float* __restrict__ bound2,
    float* __restrict__ out)
{
    __shared__ float xs[64][ROWPAD];                       // 41.2 KB
    __shared__ __align__(16) float w1s[MOUT][NBT][NBT];    // 9.2 KB
    __shared__ __align__(16) float wfs[MOUT][NBT];         // 576 B
    __shared__ float ob[576];                              // 2.3 KB

    const int tid = threadIdx.x;
    const int pj  = blockIdx.x;       // 0..639
    const int p   = pj / NB1;
    const int j   = pj - p * NB1;

    // ---- stage all 64 batch rows of patch p (coalesced float4)
    for (int i = tid; i < 64 * (ROWLEN / 4); i += 576) {
        const int b4 = i / 40;
        const int c4 = (i - b4 * 40) * 4;
        const float4 v = *reinterpret_cast<const float4*>(
            x + (size_t)b4 * (NPATCH * ROWLEN) + p * ROWLEN + c4);
        xs[b4][c4 + 0] = v.x;
        xs[b4][c4 + 1] = v.y;
        xs[b4][c4 + 2] = v.z;
        xs[b4][c4 + 3] = v.w;
    }

    // ---- batch-independent W1 / Wf tables for this (p,j)  (exactly 4 iters)
    const int bb = pj * MOUT;
    for (int i = tid; i < MOUT * NBT * NBT; i += 576) {
        const int mi = i >> 8;
        const int r  = i & 255;
        const int t  = r >> 4;
        const int s  = r & 15;
        const float b1v = bound1[bb + mi];
        const float b2v = bound2[bb + mi];
        const float Ws  = fminf(b1v, b2v);                  // W_start
        const float z   = ((float)s - Ws) * ((float)t - EPS2f - (float)s);
        w1s[mi][t][s] = __builtin_amdgcn_rcpf(1.0f + __expf(-z));
    }
    if (tid < MOUT * NBT) {
        const int mi = tid >> 4;
        const int t  = tid & 15;
        const float b1v = bound1[bb + mi];
        const float b2v = bound2[bb + mi];
        const float Ws  = fminf(b1v, b2v);
        const float We  = fmaxf(b1v, b2v);                  // W_end
        const float z   = ((float)t - Ws) * (We - (float)t);
        wfs[mi][t] = __builtin_amdgcn_rcpf(1.0f + __expf(-z));
    }

    __syncthreads();

    // ---- compute: wave = m, lane = batch
    const int m    = tid >> 6;        // 0..8
    const int lane = tid & 63;        // batch
    const int k    = (m < j) ? m : m + 1;   // kidx[j][m]

    // na2 = (x_other - 1) pairs : 16 VGPRs. addr stride 161 -> 2-way = free.
    f32x2 na2[8];
    #pragma unroll
    for (int q = 0; q < 8; ++q) {
        f32x2 v;
        v.x = xs[lane][(2 * q + 0) * NB1 + k] - 1.0f;
        v.y = xs[lane][(2 * q + 1) * NB1 + k] - 1.0f;
        na2[q] = v;
    }

    const f32x2 one2 = {1.0f, 1.0f};
    const float4* w1row = reinterpret_cast<const float4*>(&w1s[m][0][0]);

    float qacc = 1.0f;
    #pragma unroll
    for (int t = 0; t < NBT; ++t) {
        // 4 wave-uniform ds_read_b128 (broadcast)
        const float4 wa = w1row[t * 4 + 0];
        const float4 wb = w1row[t * 4 + 1];
        const float4 wc = w1row[t * 4 + 2];
        const float4 wd = w1row[t * 4 + 3];

        // X1 pairs = 1 - (1-x)*W1 via packed fma (na = x-1): 8 pk_fma
        const f32x2 e0 = pk_fma(na2[0], f32x2{wa.x, wa.y}, one2);
        const f32x2 e1 = pk_fma(na2[1], f32x2{wa.z, wa.w}, one2);
        const f32x2 e2 = pk_fma(na2[2], f32x2{wb.x, wb.y}, one2);
        const f32x2 e3 = pk_fma(na2[3], f32x2{wb.z, wb.w}, one2);
        const f32x2 e4 = pk_fma(na2[4], f32x2{wc.x, wc.y}, one2);
        const f32x2 e5 = pk_fma(na2[5], f32x2{wc.z, wc.w}, one2);
        const f32x2 e6 = pk_fma(na2[6], f32x2{wd.x, wd.y}, one2);
        const f32x2 e7 = pk_fma(na2[7], f32x2{wd.z, wd.w}, one2);

        // packed product tree: 7 pk_mul + 1 scalar mul
        const f32x2 m0 = pk_mul(e0, e1);
        const f32x2 m1 = pk_mul(e2, e3);
        const f32x2 m2 = pk_mul(e4, e5);
        const f32x2 m3 = pk_mul(e6, e7);
        const f32x2 n0 = pk_mul(m0, m1);
        const f32x2 n1 = pk_mul(m2, m3);
        const f32x2 r  = pk_mul(n0, n1);
        const float pr = r.x * r.y;                 // prod_s X1

        // x_layer2 = 1/(1 - ln P); P=0 -> log2=-inf -> rcp(+inf)=0 (exact limit)
        const float lp2 = __log2f(pr);
        const float xl2 = __builtin_amdgcn_rcpf(fmaf(-LN2f, lp2, 1.0f));

        // re-read per t (saves 32 VGPRs vs caching):
        const float xt_t = xs[lane][t * NB1 + j];   // per-lane, conflict-free
        const float wf_t = wfs[m][t];               // wave-uniform broadcast
        const float u    = xt_t * xl2 * wf_t;
        qacc = fmaf(-qacc, u, qacc);                // qacc *= (1 - u)
    }

    // out = 1 + 1/(S-1), S = ln qacc; qacc=0 -> rcp(-inf)=-0 -> out=1 (limit)
    const float S     = LN2f * __log2f(qacc);
    const float out_v = 1.0f + __builtin_amdgcn_rcpf(S - 1.0f);

    ob[lane * MOUT + m] = out_v;      // stride 9, gcd(9,32)=1 -> 2-way = free
    __syncthreads();

    // consecutive lanes -> consecutive flat out indices (9-float row chunks)
    {
        const int bo = tid / MOUT;
        const int mo = tid - bo * MOUT;
        out[(size_t)bo * OUTD + bb + mo] = ob[tid];
    }
}

extern "C" void kernel_launch(void* const* d_in, const int* in_sizes, int n_in,
                              void* d_out, int out_size, void* d_ws, size_t ws_size,
                              hipStream_t stream) {
    const float* x  = (const float*)d_in[0];
    const float* b1 = (const float*)d_in[1];
    const float* b2 = (const float*)d_in[2];
    float* out = (float*)d_out;
    until_kernel<<<dim3(NPATCH * NB1), dim3(576), 0, stream>>>(x, b1, b2, out);
}